// Round 14
// baseline (1511.015 us; speedup 1.0000x reference)
//
#include <hip/hip_runtime.h>
#include <math.h>

typedef _Float16 f16;
typedef _Float16 f16x2 __attribute__((ext_vector_type(2)));
typedef _Float16 f16x8 __attribute__((ext_vector_type(8)));
typedef float f32x4 __attribute__((ext_vector_type(4)));
typedef unsigned long long u64;

#define LDIM 128
#define HOUT 256

// LDS (bytes):
//  h-panels 2 x 9216 @ 0, 9216   -- [18 rows][256 c] f16, row 512 B (single plane)
//  x-panels 2 x 4608 @ 18432     -- [18 rows][128 c] f16, row 256 B (single plane)
// Row r <-> column l0 - 1 + r. 16B-granule XOR swizzle: granule ^= (row & 7).
#define XB 18432

__device__ __forceinline__ float tanh_fast(float x) {
    float a = fabsf(x);
    float e = __expf(-2.0f * a);
    float r = (1.0f - e) / (1.0f + e);
    return copysignf(r, x);
}

__device__ __forceinline__ void st_mb(u64* p, u64 v) {
    __hip_atomic_store(p, v, __ATOMIC_RELAXED, __HIP_MEMORY_SCOPE_AGENT);
}
__device__ __forceinline__ u64 ld_mb(const u64* p) {
    return __hip_atomic_load(p, __ATOMIC_RELAXED, __HIP_MEMORY_SCOPE_AGENT);
}

// A-frag packings (f16) — unchanged:
//  wt_i: [(((s*4+kk)*16+h16)*64+lane)*8+j] = W_i[h16*16+(lane&15)][kk*32+(lane>>4)*8+j][s]
//  wt_h: [(((s*8+kk)*16+h16)*64+lane)*8+j] = W_h[h16*16+(lane&15)][kk*32+(lane>>4)*8+j][s]
__global__ void prep_w(const float* __restrict__ wi, f16* __restrict__ wtif,
                       const float* __restrict__ wh, f16* __restrict__ wthf)
{
    int idx = blockIdx.x * 256 + threadIdx.x;
    const int ni = 3 * 4 * 16 * 64 * 8;      // 98304
    if (idx < ni) {
        int j    = idx & 7;
        int lane = (idx >> 3) & 63;
        int h16  = (idx >> 9) & 15;
        int kk   = (idx >> 13) & 3;
        int s    = idx >> 15;
        int h = h16 * 16 + (lane & 15);
        int c = kk * 32 + (lane >> 4) * 8 + j;
        wtif[idx] = (f16)wi[(h * 128 + c) * 3 + s];
    } else {
        int e = idx - ni;
        if (e >= 3 * 8 * 16 * 64 * 8) return;  // 196608
        int j    = e & 7;
        int lane = (e >> 3) & 63;
        int h16  = (e >> 9) & 15;
        int kk   = (e >> 13) & 7;
        int s    = e >> 16;
        int h = h16 * 16 + (lane & 15);
        int c = kk * 32 + (lane >> 4) * 8 + j;
        wthf[e] = (f16)wh[(h * 256 + c) * 3 + s];
    }
}

// stage x[b][t2][128 c][l0-1 .. l0+16] -> x-panel (single f16, swizzled); 256 threads
__device__ __forceinline__ void stage_x(char* xp, const float* __restrict__ xt,
                                        int l0, int tid)
{
    const int c = tid & 127, half = tid >> 7;
#pragma unroll
    for (int i = 0; i < 9; ++i) {
        int row = half * 9 + i;              // 0..17
        int col = l0 - 1 + row;
        float xx = ((unsigned)col < 128u) ? xt[c * LDIM + col] : 0.f;
        int off = row * 256 + ((((c >> 3) ^ (row & 7)) << 4)) + (c & 7) * 2;
        *(f16*)(xp + off) = (f16)xx;
    }
}

// ---------------- Fused persistent kernel ----------------
// 128 blocks = 16 b x 8 l-windows; 256 thr = 4 waves (1 wave/SIMD -> 512-VGPR budget).
// Wave owns 64 h (h16 = wid*4 + hf, hf 0..3). wt_h A-frags REGISTER-RESIDENT (384 VGPR);
// wt_i streams from L2 (48 frags/wave/step, batchable with the big register budget).
// Cross-block handoff: R12's proven self-timestamped per-step halo mailbox
// (u64 {tag, f32 bits}, relaxed sc1 atomics, double-buffered by t&1; measured cost ~0).
__global__ void __launch_bounds__(256, 1)
rnn_fused(const float* __restrict__ x, const f16* __restrict__ wti,
          const f16* __restrict__ wth, float* __restrict__ out,
          u64* __restrict__ mbox)
{
    __shared__ __align__(16) char smem[27648];
    const int tid  = threadIdx.x;
    const int lane = tid & 63, wid = tid >> 6;   // 4 waves
    const int b    = blockIdx.x & 15;
    const int lw   = blockIdx.x >> 4;            // 0..7
    const int l0   = lw * 16;
    const int l16  = lane & 15, g = lane >> 4;
    const long HL  = (long)HOUT * LDIM;
    float* outb    = out + (long)b * (64 * HL);
    const float* xb = x + (long)b * (64L * 128 * LDIM);

    // publish duty for this thread's column (l0 + l16)
    int edge = -1;
    if (l16 == 0  && lw > 0) edge = 0;   // left edge -> consumed by lw-1
    if (l16 == 15 && lw < 7) edge = 1;   // right edge -> consumed by lw+1
    u64* mb_pub = (edge >= 0) ? (mbox + (((b * 8 + lw) * 2 + edge) * 2) * 256) : nullptr;

    // ---- wt_h A-frags resident: 3 s x 8 kk x 4 hf = 96 f16x8 = 384 VGPR
    f16x8 afrh[3][8][4];
#pragma unroll
    for (int s = 0; s < 3; ++s)
#pragma unroll
        for (int kk = 0; kk < 8; ++kk)
#pragma unroll
            for (int hf = 0; hf < 4; ++hf)
                afrh[s][kk][hf] = *(const f16x8*)(wth +
                    ((((s * 8 + kk) * 16 + wid * 4 + hf) * 64 + lane) << 3));

    // ---- prologue: stage x[0]
    stage_x(smem + XB, xb, l0, tid);
    __syncthreads();

    for (int t = 0; t < 64; ++t) {
        float* outt = outb + (long)t * HL;

        // ---- stage x[t+1] into the other x-buffer
        if (t + 1 < 64)
            stage_x(smem + XB + ((t + 1) & 1) * 4608,
                    xb + (long)(t + 1) * (128 * LDIM), l0, tid);

        // ---- acc = Z_t (zconv from x-buffer t&1; wt_i streamed from L2)
        f32x4 acc[4] = {};
        {
            const char* xp = smem + XB + (t & 1) * 4608;
#pragma unroll
            for (int kk = 0; kk < 4; ++kk)
#pragma unroll
                for (int s = 0; s < 3; ++s) {
                    f16x8 a0 = *(const f16x8*)(wti +
                        ((((s * 4 + kk) * 16 + wid * 4 + 0) * 64 + lane) << 3));
                    f16x8 a1 = *(const f16x8*)(wti +
                        ((((s * 4 + kk) * 16 + wid * 4 + 1) * 64 + lane) << 3));
                    f16x8 a2 = *(const f16x8*)(wti +
                        ((((s * 4 + kk) * 16 + wid * 4 + 2) * 64 + lane) << 3));
                    f16x8 a3 = *(const f16x8*)(wti +
                        ((((s * 4 + kk) * 16 + wid * 4 + 3) * 64 + lane) << 3));
                    int r = l16 + s;
                    int base = r * 256 + ((((kk * 4 + g) ^ (r & 7)) << 4));
                    f16x8 bb = *(const f16x8*)(xp + base);
                    acc[0] = __builtin_amdgcn_mfma_f32_16x16x32_f16(a0, bb, acc[0], 0, 0, 0);
                    acc[1] = __builtin_amdgcn_mfma_f32_16x16x32_f16(a1, bb, acc[1], 0, 0, 0);
                    acc[2] = __builtin_amdgcn_mfma_f32_16x16x32_f16(a2, bb, acc[2], 0, 0, 0);
                    acc[3] = __builtin_amdgcn_mfma_f32_16x16x32_f16(a3, bb, acc[3], 0, 0, 0);
                }
        }

        char* hp = smem + ((t ^ 1) & 1) * 9216;   // panel holding h_{t-1}

        // ---- h-conv s=1 (rows 1..16: own columns, no halo), resident weights
        if (t > 0) {
#pragma unroll
            for (int kk = 0; kk < 8; ++kk) {
                int r = l16 + 1;
                int base = r * 512 + ((((kk * 4 + g) ^ (r & 7)) << 4));
                f16x8 bb = *(const f16x8*)(hp + base);
#pragma unroll
                for (int hf = 0; hf < 4; ++hf)
                    acc[hf] = __builtin_amdgcn_mfma_f32_16x16x32_f16(
                        afrh[1][kk][hf], bb, acc[hf], 0, 0, 0);
            }
        }

        // ---- halo: poll self-timestamped mailbox (tag >= t), write rows 0 / 17
        if (t > 0) {
            const int par = (t ^ 1) & 1;           // slot parity of h_{t-1}
#pragma unroll
            for (int side = 0; side < 2; ++side) {
                int c = tid;                       // 0..255 (h row)
                int nb = lw + (side ? 1 : -1);
                float xx = 0.f;
                if ((unsigned)nb < 8u) {
                    const u64* p = mbox +
                        ((((b * 8 + nb) * 2 + (side ? 0 : 1)) * 2 + par) * 256) + c;
                    u64 v = ld_mb(p);
                    while ((unsigned)(v >> 32) < (unsigned)t) {
                        __builtin_amdgcn_s_sleep(1);
                        v = ld_mb(p);
                    }
                    xx = __uint_as_float((unsigned)v);
                }
                int row = side ? 17 : 0;
                int off = row * 512 + ((((c >> 3) ^ (row & 7)) << 4)) + (c & 7) * 2;
                *(f16*)(hp + off) = (f16)xx;
            }
        }
        __syncthreads();   // halo rows visible to all waves

        // ---- h-conv s=0,2 (use halo rows), resident weights
        if (t > 0) {
#pragma unroll
            for (int kk = 0; kk < 8; ++kk)
#pragma unroll
                for (int sp = 0; sp < 2; ++sp) {
                    int s = sp * 2;                // 0, 2
                    int r = l16 + s;
                    int base = r * 512 + ((((kk * 4 + g) ^ (r & 7)) << 4));
                    f16x8 bb = *(const f16x8*)(hp + base);
#pragma unroll
                    for (int hf = 0; hf < 4; ++hf)
                        acc[hf] = __builtin_amdgcn_mfma_f32_16x16x32_f16(
                            afrh[s][kk][hf], bb, acc[hf], 0, 0, 0);
                }
        }

        // ---- epilogue: h_t = tanh(acc); publish edges first, then out + panel
        char* pw = smem + (t & 1) * 9216;
        u64* pub = (edge >= 0) ? (mb_pub + (t & 1) * 256) : nullptr;
        const u64 tagw = ((u64)(unsigned)(t + 1)) << 32;
        const int rw = l16 + 1;
        const int rx = rw & 7;
        float hv[4][4];
#pragma unroll
        for (int hf = 0; hf < 4; ++hf)
#pragma unroll
            for (int vv = 0; vv < 4; ++vv)
                hv[hf][vv] = tanh_fast(acc[hf][vv]);

        if (edge >= 0) {
#pragma unroll
            for (int hf = 0; hf < 4; ++hf)
#pragma unroll
                for (int vv = 0; vv < 4; ++vv) {
                    int c = wid * 64 + hf * 16 + g * 4 + vv;
                    st_mb(&pub[c], tagw | (u64)__float_as_uint(hv[hf][vv]));
                }
        }
#pragma unroll
        for (int hf = 0; hf < 4; ++hf)
#pragma unroll
            for (int vv = 0; vv < 4; ++vv) {
                int c = wid * 64 + hf * 16 + g * 4 + vv;
                outt[(long)c * LDIM + l0 + l16] = hv[hf][vv];   // plain store
            }
#pragma unroll
        for (int hf = 0; hf < 4; ++hf)
#pragma unroll
            for (int p = 0; p < 2; ++p) {
                int c = wid * 64 + hf * 16 + g * 4 + p * 2;
                int off = rw * 512 + ((((c >> 3) ^ rx) << 4)) + (c & 7) * 2;
                f16x2 hw; hw[0] = (f16)hv[hf][2 * p]; hw[1] = (f16)hv[hf][2 * p + 1];
                *(f16x2*)(pw + off) = hw;
            }

        __syncthreads();   // h_t panel + x-stage complete before next step
    }
}

extern "C" void kernel_launch(void* const* d_in, const int* in_sizes, int n_in,
                              void* d_out, int out_size, void* d_ws, size_t ws_size,
                              hipStream_t stream)
{
    const float* x   = (const float*)d_in[0];   // [16][64][128][128]
    const float* W_i = (const float*)d_in[1];   // [256][128][3]
    const float* W_h = (const float*)d_in[2];   // [256][256][3]
    float* out = (float*)d_out;                 // [16][64][256][128]

    f16* wt_i = (f16*)d_ws;                              // 196608 B
    f16* wt_h = (f16*)((char*)d_ws + 196608);            // 393216 B
    u64* mbox = (u64*)((char*)d_ws + 589824);            // 16*8*2*2*256*8 = 131072 B

    prep_w<<<1152, 256, 0, stream>>>(W_i, wt_i, W_h, wt_h);
    hipMemsetAsync(mbox, 0, 131072, stream);             // tags <- 0

    rnn_fused<<<128, 256, 0, stream>>>(x, wt_i, wt_h, out, mbox);
}

// Round 15
// 423.287 us; speedup vs baseline: 3.5697x; 3.5697x over previous
//
#include <hip/hip_runtime.h>
#include <math.h>

typedef _Float16 f16;
typedef _Float16 f16x2 __attribute__((ext_vector_type(2)));
typedef _Float16 f16x8 __attribute__((ext_vector_type(8)));
typedef float f32x4 __attribute__((ext_vector_type(4)));
typedef unsigned long long u64;

#define LDIM 128
#define HOUT 256

// LDS (bytes):
//  WH @ 0      : wt_h quarter slice, 96 frags x 1024 B = 98304 (frag = (s*8+kk)*4 + hl)
//  HP @ 98304  : h-panel [34 rows][256 c] f16, row 512 B = 17408 (row = col - (L0-1))
//  XP @ 115712 : x-panels 2 x [34 rows][128 c] f16, row 256 B = 2 x 8704
// 16B-granule XOR swizzle everywhere: granule ^= (row & 7). Total 133120 B (1 block/CU).
#define WH 0
#define HP 98304
#define XP 115712

__device__ __forceinline__ float tanh_fast(float x) {
    float a = fabsf(x);
    float e = __expf(-2.0f * a);
    float r = (1.0f - e) / (1.0f + e);
    return copysignf(r, x);
}

__device__ __forceinline__ void st_mb(u64* p, u64 v) {
    __hip_atomic_store(p, v, __ATOMIC_RELAXED, __HIP_MEMORY_SCOPE_AGENT);
}
__device__ __forceinline__ u64 ld_mb(const u64* p) {
    return __hip_atomic_load(p, __ATOMIC_RELAXED, __HIP_MEMORY_SCOPE_AGENT);
}
__device__ __forceinline__ u64 pack_h2(float a, float b) {
    f16x2 t; t[0] = (f16)a; t[1] = (f16)b;
    unsigned u; __builtin_memcpy(&u, &t, 4);
    return (u64)u;
}

// A-frag packings (f16) — unchanged:
//  wt_i: [(((s*4+kk)*16+h16)*64+lane)*8+j] = W_i[h16*16+(lane&15)][kk*32+(lane>>4)*8+j][s]
//  wt_h: [(((s*8+kk)*16+h16)*64+lane)*8+j] = W_h[h16*16+(lane&15)][kk*32+(lane>>4)*8+j][s]
__global__ void prep_w(const float* __restrict__ wi, f16* __restrict__ wtif,
                       const float* __restrict__ wh, f16* __restrict__ wthf)
{
    int idx = blockIdx.x * 256 + threadIdx.x;
    const int ni = 3 * 4 * 16 * 64 * 8;      // 98304
    if (idx < ni) {
        int j    = idx & 7;
        int lane = (idx >> 3) & 63;
        int h16  = (idx >> 9) & 15;
        int kk   = (idx >> 13) & 3;
        int s    = idx >> 15;
        int h = h16 * 16 + (lane & 15);
        int c = kk * 32 + (lane >> 4) * 8 + j;
        wtif[idx] = (f16)wi[(h * 128 + c) * 3 + s];
    } else {
        int e = idx - ni;
        if (e >= 3 * 8 * 16 * 64 * 8) return;  // 196608
        int j    = e & 7;
        int lane = (e >> 3) & 63;
        int h16  = (e >> 9) & 15;
        int kk   = (e >> 13) & 7;
        int s    = e >> 16;
        int h = h16 * 16 + (lane & 15);
        int c = kk * 32 + (lane >> 4) * 8 + j;
        wthf[e] = (f16)wh[(h * 256 + c) * 3 + s];
    }
}

// stage x[b][t2][128 c][L0-1 .. L0+32] -> x-panel (single f16, swizzled)
__device__ __forceinline__ void stage_x(char* xp, const float* __restrict__ xt,
                                        int L0, int tid)
{
    const int c = tid & 127, half = tid >> 7;
#pragma unroll
    for (int i = 0; i < 17; ++i) {
        int row = half * 17 + i;             // 0..33
        int col = L0 - 1 + row;
        float xx = ((unsigned)col < 128u) ? xt[c * LDIM + col] : 0.f;
        int off = row * 256 + ((((c >> 3) ^ (row & 7)) << 4)) + (c & 7) * 2;
        *(f16*)(xp + off) = (f16)xx;
    }
}

// ---------------- Persistent kernel: LDS-resident wt_h, h-split across blocks ----------------
// 256 blocks = 16 b x 4 lw (32-col windows) x 4 hq (64 h each); 256 thr = 4 waves.
// Wave wid computes h16 = hq*4 + wid for both 16-col tiles of the window.
// Per step: zconv (wt_i streamed, 12 KB/wave) + hconv (weights from LDS, zero L2).
// h_{t-1} exchange: self-timestamped mailbox, 1024 u64 core tile per (block, parity);
// consumer reads 3 sibling tiles + 2 halo column slices = 3328 u64 (13/thread).
__global__ void __launch_bounds__(256, 1)
rnn_fused(const float* __restrict__ x, const f16* __restrict__ wti,
          const f16* __restrict__ wth, float* __restrict__ out,
          u64* __restrict__ mbox)
{
    __shared__ __align__(16) char smem[133120];
    const int tid  = threadIdx.x;
    const int lane = tid & 63, wid = tid >> 6;   // 4 waves
    const int bid  = blockIdx.x;
    const int b    = bid >> 4;
    const int lw   = (bid >> 2) & 3;
    const int hq   = bid & 3;
    const int L0   = lw * 32;
    const int l16  = lane & 15, g = lane >> 4;
    const long HL  = (long)HOUT * LDIM;
    float* outb    = out + (long)b * (64 * HL);
    const float* xb = x + (long)b * (64L * 128 * LDIM);

    // ---- prologue: wt_h quarter -> LDS (once)
    for (int i = tid; i < 6144; i += 256) {
        int frag = i >> 6, ln = i & 63;
        int s = frag >> 5, kk = (frag >> 2) & 7, hl = frag & 3;
        f16x8 v = *(const f16x8*)(wth +
            ((((s * 8 + kk) * 16 + hq * 4 + hl) * 64 + ln) << 3));
        *(f16x8*)(smem + WH + frag * 1024 + ln * 16) = v;
    }
    // zero h-panel rows 0 / 33 (stay zero for edge lw; rewritten via mailbox otherwise)
    {
        int c = tid;
        int o0 = (((c >> 3) ^ 0) << 4) + (c & 7) * 2;
        *(f16*)(smem + HP + o0) = (f16)0.f;
        int o1 = 33 * 512 + (((c >> 3) ^ 1) << 4) + (c & 7) * 2;   // 33&7 = 1
        *(f16*)(smem + HP + o1) = (f16)0.f;
    }
    stage_x(smem + XP, xb, L0, tid);
    __syncthreads();

    for (int t = 0; t < 64; ++t) {
        float* outt = outb + (long)t * HL;

        // ---- stage x[t+1] into the other x-buffer
        if (t + 1 < 64)
            stage_x(smem + XP + ((t + 1) & 1) * 8704,
                    xb + (long)(t + 1) * (128 * LDIM), L0, tid);

        // ---- zconv: acc = Z_t (wt_i streamed from L2; both tiles share A-frag)
        f32x4 acc[2] = {};
        {
            const char* xp = smem + XP + (t & 1) * 8704;
#pragma unroll
            for (int kk = 0; kk < 4; ++kk)
#pragma unroll
                for (int s = 0; s < 3; ++s) {
                    f16x8 a = *(const f16x8*)(wti +
                        ((((s * 4 + kk) * 16 + hq * 4 + wid) * 64 + lane) << 3));
#pragma unroll
                    for (int tau = 0; tau < 2; ++tau) {
                        int r = 16 * tau + l16 + s;
                        int base = r * 256 + ((((kk * 4 + g) ^ (r & 7)) << 4));
                        f16x8 bb = *(const f16x8*)(xp + base);
                        acc[tau] = __builtin_amdgcn_mfma_f32_16x16x32_f16(a, bb, acc[tau], 0, 0, 0);
                    }
                }
        }

        // ---- mailbox consume: h_{t-1} tiles of 3 hq-siblings + 2 halo columns
        if (t > 0) {
            const int par = (t ^ 1) & 1;
            int offs[13]; u64 vals[13];
#pragma unroll
            for (int q = 0; q < 13; ++q) {
                int j = tid + q * 256;
                int off = -1;
                if (j < 3072) {
                    int sib = j >> 10, w = j & 1023;
                    int hq2 = sib + (sib >= hq ? 1 : 0);
                    off = (((b * 4 + lw) * 4 + hq2) * 2 + par) * 1024 + w;
                } else {
                    int e2 = j - 3072, side = e2 >> 7, idx = e2 & 127;
                    int nlw = lw + (side ? 1 : -1);
                    if ((unsigned)nlw < 4u)
                        off = (((b * 4 + nlw) * 4 + (idx >> 5)) * 2 + par) * 1024
                            + (side ? (idx & 31) : (31 * 32 + (idx & 31)));
                }
                offs[q] = off;
                vals[q] = (off >= 0) ? ld_mb(mbox + off) : ~0ull;
            }
            for (;;) {
                bool all = true;
#pragma unroll
                for (int q = 0; q < 13; ++q)
                    if ((unsigned)(vals[q] >> 32) < (unsigned)t) {
                        all = false;
                        vals[q] = ld_mb(mbox + offs[q]);
                    }
                if (all) break;
                __builtin_amdgcn_s_sleep(1);
            }
#pragma unroll
            for (int q = 0; q < 13; ++q) {
                if (offs[q] < 0) continue;
                int j = tid + q * 256;
                int row, c;
                if (j < 3072) {
                    int sib = j >> 10, w = j & 1023;
                    int hq2 = sib + (sib >= hq ? 1 : 0);
                    row = (w >> 5) + 1;
                    c = hq2 * 64 + (w & 31) * 2;
                } else {
                    int e2 = j - 3072, side = e2 >> 7, idx = e2 & 127;
                    row = side ? 33 : 0;
                    c = (idx >> 5) * 64 + (idx & 31) * 2;
                }
                unsigned pk = (unsigned)vals[q];
                int off = row * 512 + ((((c >> 3) ^ (row & 7)) << 4)) + (c & 7) * 2;
                f16x2 w2; __builtin_memcpy(&w2, &pk, 4);
                *(f16x2*)(smem + HP + off) = w2;
            }
        }
        __syncthreads();   // h-panel complete (own part from t-1 epilogue, rest above)

        // ---- hconv: weights from LDS, B from h-panel
        if (t > 0) {
#pragma unroll
            for (int kk = 0; kk < 8; ++kk)
#pragma unroll
                for (int s = 0; s < 3; ++s) {
                    f16x8 a = *(const f16x8*)(smem + WH +
                        ((s * 8 + kk) * 4 + wid) * 1024 + lane * 16);
#pragma unroll
                    for (int tau = 0; tau < 2; ++tau) {
                        int r = 16 * tau + l16 + s;
                        int base = r * 512 + ((((kk * 4 + g) ^ (r & 7)) << 4));
                        f16x8 bb = *(const f16x8*)(smem + HP + base);
                        acc[tau] = __builtin_amdgcn_mfma_f32_16x16x32_f16(a, bb, acc[tau], 0, 0, 0);
                    }
                }
        }
        __syncthreads();   // all panel reads done before epilogue rewrites own region

        // ---- epilogue: h_t = tanh(acc); publish first, then out + own panel region
        float hv[2][4];
#pragma unroll
        for (int tau = 0; tau < 2; ++tau)
#pragma unroll
            for (int vv = 0; vv < 4; ++vv)
                hv[tau][vv] = tanh_fast(acc[tau][vv]);

        if (t < 63) {
            u64* pub = mbox + (long)((((b * 4 + lw) * 4 + hq) * 2 + (t & 1))) * 1024;
            const u64 tagw = ((u64)(unsigned)(t + 1)) << 32;
#pragma unroll
            for (int tau = 0; tau < 2; ++tau)
#pragma unroll
                for (int p = 0; p < 2; ++p) {
                    int col = 16 * tau + l16;
                    int hpair = wid * 8 + g * 2 + p;
                    st_mb(&pub[col * 32 + hpair],
                          tagw | pack_h2(hv[tau][2 * p], hv[tau][2 * p + 1]));
                }
        }
#pragma unroll
        for (int tau = 0; tau < 2; ++tau)
#pragma unroll
            for (int vv = 0; vv < 4; ++vv) {
                int ch = hq * 64 + wid * 16 + g * 4 + vv;
                outt[(long)ch * LDIM + L0 + 16 * tau + l16] = hv[tau][vv];
            }
#pragma unroll
        for (int tau = 0; tau < 2; ++tau) {
            int rw = 16 * tau + l16 + 1;
            int rx = rw & 7;
#pragma unroll
            for (int p = 0; p < 2; ++p) {
                int c = hq * 64 + wid * 16 + g * 4 + 2 * p;
                int off = rw * 512 + ((((c >> 3) ^ rx) << 4)) + (c & 7) * 2;
                f16x2 w2; w2[0] = (f16)hv[tau][2 * p]; w2[1] = (f16)hv[tau][2 * p + 1];
                *(f16x2*)(smem + HP + off) = w2;
            }
        }
        // no barrier here: next iteration's first barrier orders these LDS writes
    }
}

extern "C" void kernel_launch(void* const* d_in, const int* in_sizes, int n_in,
                              void* d_out, int out_size, void* d_ws, size_t ws_size,
                              hipStream_t stream)
{
    const float* x   = (const float*)d_in[0];   // [16][64][128][128]
    const float* W_i = (const float*)d_in[1];   // [256][128][3]
    const float* W_h = (const float*)d_in[2];   // [256][256][3]
    float* out = (float*)d_out;                 // [16][64][256][128]

    f16* wt_i = (f16*)d_ws;                              // 196608 B
    f16* wt_h = (f16*)((char*)d_ws + 196608);            // 393216 B
    u64* mbox = (u64*)((char*)d_ws + 589824);            // 256 blk x 2 par x 1024 x 8 = 4 MB

    prep_w<<<1152, 256, 0, stream>>>(W_i, wt_i, W_h, wt_h);
    hipMemsetAsync(mbox, 0, 4194304, stream);            // tags <- 0

    rnn_fused<<<256, 256, 0, stream>>>(x, wt_i, wt_h, out, mbox);
}